// Round 10
// baseline (102.778 us; speedup 1.0000x reference)
//
#include <hip/hip_runtime.h>
#include <math.h>

#define BN_EPS 0.001f
#define CHUNK 4096          // edges per chunk; nchunk = ceil(ne/CHUNK) must be <= 256
#define MAXBUCK 1024        // nbuck = ceil(n/64) must be <= 1024

typedef __attribute__((ext_vector_type(8))) short bf16x8;
typedef __attribute__((ext_vector_type(4))) float f32x4;
typedef __attribute__((ext_vector_type(2))) float f32x2;

__device__ inline unsigned bf16rne(float f) {
  unsigned u = __float_as_uint(f);
  return (u + 0x7fffu + ((u >> 16) & 1u)) >> 16;
}

// ---------------- pass 1: per-chunk LDS histogram by bucket (src>>6) ----------------
__global__ __launch_bounds__(256) void k_ehist(const int2* __restrict__ ep, int ne,
                                               int nbuck, int* __restrict__ ghist) {
  __shared__ int h[MAXBUCK];
  int c = blockIdx.x, t = threadIdx.x;
  for (int i = t; i < nbuck; i += 256) h[i] = 0;
  __syncthreads();
  int base = c * CHUNK;
  int end = min(base + CHUNK, ne);
  for (int e = base + t; e < end; e += 256) atomicAdd(&h[ep[e].x >> 6], 1);
  __syncthreads();
  int* row = ghist + (size_t)c * nbuck;
  for (int i = t; i < nbuck; i += 256) row[i] = h[i];
}

// ---------------- pass 2a: per-bucket exclusive scan over chunks (in place) + totals ----
__global__ __launch_bounds__(256) void k_bscan(int* __restrict__ ghist, int nchunk,
                                               int nbuck, int* __restrict__ btot) {
  __shared__ int s0[256], s1[256];
  int b = blockIdx.x, t = threadIdx.x;
  int v = (t < nchunk) ? ghist[(size_t)t * nbuck + b] : 0;
  s0[t] = v;
  __syncthreads();
  int* src = s0; int* dst = s1;
  for (int off = 1; off < 256; off <<= 1) {
    int x = src[t];
    if (t >= off) x += src[t - off];
    dst[t] = x;
    __syncthreads();
    int* tmp = src; src = dst; dst = tmp;
  }
  if (t < nchunk) ghist[(size_t)t * nbuck + b] = src[t] - v;  // exclusive
  if (t == 0) btot[b] = src[255];                             // total
}

// ---------------- pass 2b: single-block exclusive scan of bucket totals ----------------
__global__ __launch_bounds__(1024) void k_bbase(const int* __restrict__ btot, int nbuck,
                                                int* __restrict__ bbase) {
  __shared__ int s0[1024], s1[1024];
  int t = threadIdx.x;
  int v = (t < nbuck) ? btot[t] : 0;
  s0[t] = v;
  __syncthreads();
  int* src = s0; int* dst = s1;
  for (int off = 1; off < 1024; off <<= 1) {
    int x = src[t];
    if (t >= off) x += src[t - off];
    dst[t] = x;
    __syncthreads();
    int* tmp = src; src = dst; dst = tmp;
  }
  if (t < nbuck) bbase[t] = src[t] - v;
}

// ---------------- pass 3: write packed records to exact slots (LDS cursors) ----------
// record: bits[16:0] = dst, bits[22:17] = src & 63
__global__ __launch_bounds__(256) void k_ebin(const int2* __restrict__ ep, int ne,
                                              int nbuck, const int* __restrict__ ghist,
                                              const int* __restrict__ bbase,
                                              unsigned* __restrict__ bins) {
  __shared__ int cur[MAXBUCK];
  int c = blockIdx.x, t = threadIdx.x;
  const int* row = ghist + (size_t)c * nbuck;
  for (int i = t; i < nbuck; i += 256) cur[i] = bbase[i] + row[i];
  __syncthreads();
  int base = c * CHUNK;
  int end = min(base + CHUNK, ne);
  for (int e = base + t; e < end; e += 256) {
    int2 p = ep[e];
    int pos = atomicAdd(&cur[p.x >> 6], 1);
    bins[pos] = (unsigned)p.y | ((unsigned)(p.x & 63) << 17);
  }
}

// ---------------- fused per-bucket: hist -> scan -> deg/isd/offsets -> CSR fill -------
__global__ __launch_bounds__(256) void k_bfinal(const int* __restrict__ bbase,
                                                const int* __restrict__ btot,
                                                const unsigned* __restrict__ bins,
                                                int n, int* __restrict__ deg,
                                                float* __restrict__ isd,
                                                int* __restrict__ offsets,
                                                int* __restrict__ csr_dst) {
  __shared__ int h[64];
  __shared__ int cur[64];
  int bk = blockIdx.x, t = threadIdx.x;
  if (t < 64) h[t] = 0;
  __syncthreads();
  int s = bbase[bk], cnt = btot[bk];
  for (int i = t; i < cnt; i += 256) atomicAdd(&h[bins[s + i] >> 17], 1);
  __syncthreads();
  if (t == 0) {
    int run = s;
    for (int j = 0; j < 64; ++j) { cur[j] = run; run += h[j]; }
  }
  __syncthreads();
  if (t < 64) {
    int node = (bk << 6) + t;
    if (node < n) {
      deg[node] = h[t];
      offsets[node] = cur[t];
      isd[node] = 1.0f / sqrtf((float)h[t]);  // deg==0 -> +inf, matches jnp.power
    }
  }
  __syncthreads();
  for (int i = t; i < cnt; i += 256) {
    unsigned r = bins[s + i];
    int pos = atomicAdd(&cur[r >> 17], 1);
    csr_dst[pos] = (int)(r & 0x1FFFFu);
  }
}

// ---------------- W split+transpose into fragment-major layout (once) ----------------
__global__ __launch_bounds__(256) void k_wsplit(const float* __restrict__ W,
                                                unsigned short* __restrict__ Wh,
                                                unsigned short* __restrict__ Wl) {
  int g = blockIdx.x * 256 + threadIdx.x;  // 0..2047
  int frag = g >> 6;                       // 0..31 = ct*4+ks
  int lane = g & 63;
  int ct = frag >> 2, ks = frag & 3;
  int col = ct * 16 + (lane & 15);
  int k0 = ks * 32 + (lane >> 4) * 8;
  unsigned short h8[8], l8[8];
#pragma unroll
  for (int j = 0; j < 8; ++j) {
    float x = W[(size_t)(k0 + j) * 128 + col];
    unsigned short h = (unsigned short)(__float_as_uint(x) >> 16);  // trunc hi
    float rem = x - __uint_as_float((unsigned)h << 16);
    h8[j] = h;
    l8[j] = (unsigned short)bf16rne(rem);
  }
  *(uint4*)&Wh[(size_t)frag * 512 + lane * 8] = *(uint4*)h8;
  *(uint4*)&Wl[(size_t)frag * 512 + lane * 8] = *(uint4*)l8;
}

// ---------------- split-bf16 MFMA GEMM: T = X @ W + b ----------------
// Wave = 32 rows x 64 cols (2 row-tiles share each B-fragment: 96 MFMA / 32 B-loads).
// Block = 4 waves = 64 rows. Writes fp32 T and fp8 Tb8 = fp8(isd[row]*t[row]).
__global__ __launch_bounds__(256, 3) void k_gemm(const float* __restrict__ X,
                                                 const unsigned short* __restrict__ Wh,
                                                 const unsigned short* __restrict__ Wl,
                                                 const float* __restrict__ b,
                                                 const float* __restrict__ isd,
                                                 float* __restrict__ T,
                                                 unsigned char* __restrict__ Tb8, int M) {
  int tid = threadIdx.x;
  int wave = tid >> 6, lane = tid & 63;
  int r16 = lane & 15, kq = lane >> 4;
  int ch = wave & 1;                               // col half: ct_global = ch*4+ct
  int rowbase = blockIdx.x * 64 + (wave >> 1) * 32;

  // load + split A fragments: rt in {0,1}, ks in 0..3
  bf16x8 ah[2][4], al[2][4];
#pragma unroll
  for (int rt = 0; rt < 2; ++rt) {
    int row = rowbase + rt * 16 + r16;
    bool ok = row < M;
    const float* xr = X + ((size_t)row << 7);
#pragma unroll
    for (int ks = 0; ks < 4; ++ks) {
      int k0 = ks * 32 + kq * 8;
      float4 v0 = ok ? *(const float4*)(xr + k0) : make_float4(0.f, 0.f, 0.f, 0.f);
      float4 v1 = ok ? *(const float4*)(xr + k0 + 4) : make_float4(0.f, 0.f, 0.f, 0.f);
      float f[8] = {v0.x, v0.y, v0.z, v0.w, v1.x, v1.y, v1.z, v1.w};
      bf16x8 h8, l8;
#pragma unroll
      for (int j = 0; j < 8; ++j) {
        unsigned short h = (unsigned short)(__float_as_uint(f[j]) >> 16);
        float rem = f[j] - __uint_as_float((unsigned)h << 16);
        h8[j] = (short)h;
        l8[j] = (short)bf16rne(rem);
      }
      ah[rt][ks] = h8;
      al[rt][ks] = l8;
    }
  }

  f32x4 acc[2][4] = {};
#pragma unroll
  for (int ks = 0; ks < 4; ++ks) {
#pragma unroll
    for (int ct = 0; ct < 4; ++ct) {
      int frag = (ch * 4 + ct) * 4 + ks;
      bf16x8 bh = *(const bf16x8*)&Wh[(size_t)frag * 512 + lane * 8];
      bf16x8 bl = *(const bf16x8*)&Wl[(size_t)frag * 512 + lane * 8];
#pragma unroll
      for (int rt = 0; rt < 2; ++rt) {
        acc[rt][ct] = __builtin_amdgcn_mfma_f32_16x16x32_bf16(ah[rt][ks], bh, acc[rt][ct], 0, 0, 0);
        acc[rt][ct] = __builtin_amdgcn_mfma_f32_16x16x32_bf16(ah[rt][ks], bl, acc[rt][ct], 0, 0, 0);
        acc[rt][ct] = __builtin_amdgcn_mfma_f32_16x16x32_bf16(al[rt][ks], bh, acc[rt][ct], 0, 0, 0);
      }
    }
  }

  // epilogue: bias, fp32 T store, fp8 byte store of isd-scaled value
  float bias[4];
#pragma unroll
  for (int ct = 0; ct < 4; ++ct) bias[ct] = b[(ch * 4 + ct) * 16 + r16];
#pragma unroll
  for (int rt = 0; rt < 2; ++rt) {
    int orow[4];
    float isdr[4];
#pragma unroll
    for (int r = 0; r < 4; ++r) {
      orow[r] = rowbase + rt * 16 + kq * 4 + r;
      isdr[r] = (orow[r] < M) ? isd[orow[r]] : 0.f;
    }
#pragma unroll
    for (int ct = 0; ct < 4; ++ct) {
      int col = (ch * 4 + ct) * 16 + r16;
#pragma unroll
      for (int r = 0; r < 4; ++r) {
        float v = acc[rt][ct][r] + bias[ct];
        if (orow[r] < M) {
          T[((size_t)orow[r] << 7) + col] = v;
          float sv = v * isdr[r];
          int pk = __builtin_amdgcn_cvt_pk_fp8_f32(sv, sv, 0, false);
          Tb8[((size_t)orow[r] << 7) + col] = (unsigned char)pk;
        }
      }
    }
  }
}

// ---------------- gather: one wave per node, fp8 rows (128B), 16 reads in flight ------
__global__ __launch_bounds__(256) void k_gather(
    const float* __restrict__ T, const unsigned char* __restrict__ Tb8,
    const int* __restrict__ deg, const float* __restrict__ isd,
    const int* __restrict__ offsets, const int* __restrict__ csr_dst,
    const float* __restrict__ mm, const float* __restrict__ var,
    const float* __restrict__ gamma, const float* __restrict__ beta,
    float* __restrict__ out, int n, int ne) {
  int wave = threadIdx.x >> 6;
  int lane = threadIdx.x & 63;
  int i = blockIdx.x * 4 + wave;
  if (i >= n) return;
  int degi = deg[i];
  int start = offsets[i];
  const unsigned short* rows = (const unsigned short*)Tb8;  // row stride 64 ushorts
  float sx[16] = {}, sy[16] = {};
  for (int e = 0; e < degi; e += 16) {
    int ii = start + e + (lane & 15);
    int dv = (ii < ne) ? csr_dst[ii] : 0;  // coalesced index load
    unsigned short r[16];
#pragma unroll
    for (int j = 0; j < 16; ++j) {
      int idx = __shfl(dv, j);
      r[j] = rows[((size_t)idx << 6) + lane];  // 2 fp8 cols per lane
    }
#pragma unroll
    for (int j = 0; j < 16; ++j) {
      int rr = (e + j < degi) ? (int)r[j] : 0;
      f32x2 f = __builtin_amdgcn_cvt_pk_f32_fp8(rr, false);
      sx[j] += f.x;
      sy[j] += f.y;
    }
  }
  float fx = (((sx[0] + sx[1]) + (sx[2] + sx[3])) + ((sx[4] + sx[5]) + (sx[6] + sx[7]))) +
             (((sx[8] + sx[9]) + (sx[10] + sx[11])) + ((sx[12] + sx[13]) + (sx[14] + sx[15])));
  float fy = (((sy[0] + sy[1]) + (sy[2] + sy[3])) + ((sy[4] + sy[5]) + (sy[6] + sy[7]))) +
             (((sy[8] + sy[9]) + (sy[10] + sy[11])) + ((sy[12] + sy[13]) + (sy[14] + sy[15])));
  float aggx = 0.f, aggy = 0.f;
  if (degi > 0) {
    float2 tv = ((const float2*)(T + ((size_t)i << 7)))[lane];
    float isi = isd[i];
    float di = (float)degi;
    aggx = 0.5f * (isi * fx) + 0.5f * (di * tv.x);
    aggy = 0.5f * (isi * fy) + 0.5f * (di * tv.y);
  }
  float2 mmv = ((const float2*)mm)[lane];
  float2 vv = ((const float2*)var)[lane];
  float2 gv = ((const float2*)gamma)[lane];
  float2 bv = ((const float2*)beta)[lane];
  float2 res;
  res.x = (aggx - mmv.x) * rsqrtf(vv.x + BN_EPS) * gv.x + bv.x;
  res.y = (aggy - mmv.y) * rsqrtf(vv.y + BN_EPS) * gv.y + bv.y;
  ((float2*)(out + ((size_t)i << 7)))[lane] = res;
}

static inline size_t align_up(size_t x) { return (x + 255) & ~(size_t)255; }

extern "C" void kernel_launch(void* const* d_in, const int* in_sizes, int n_in,
                              void* d_out, int out_size, void* d_ws, size_t ws_size,
                              hipStream_t stream) {
  const int2* ep = (const int2*)d_in[0];
  const float* X = (const float*)d_in[1];
  const float* W = (const float*)d_in[2];
  const float* b = (const float*)d_in[3];
  const float* gamma = (const float*)d_in[4];
  const float* beta = (const float*)d_in[5];
  const float* mm = (const float*)d_in[6];
  const float* var = (const float*)d_in[7];
  float* out = (float*)d_out;

  const int ne = in_sizes[0] / 2;
  const int n = in_sizes[1] / 128;
  const int nbuck = (n + 63) >> 6;              // <= MAXBUCK
  const int nchunk = (ne + CHUNK - 1) / CHUNK;  // <= 256

  char* p = (char*)d_ws;
  int* deg = (int*)p;        p += align_up((size_t)n * 4);
  float* isd = (float*)p;    p += align_up((size_t)n * 4);
  int* offsets = (int*)p;    p += align_up((size_t)n * 4);
  int* btot = (int*)p;       p += align_up((size_t)nbuck * 4);
  int* bbase = (int*)p;      p += align_up((size_t)nbuck * 4);
  int* ghist = (int*)p;      p += align_up((size_t)nchunk * nbuck * 4);
  int* csr_dst = (int*)p;    p += align_up((size_t)ne * 4);
  unsigned* bins = (unsigned*)p; p += align_up((size_t)ne * 4);
  unsigned short* Wh = (unsigned short*)p; p += align_up((size_t)128 * 128 * 2);
  unsigned short* Wl = (unsigned short*)p; p += align_up((size_t)128 * 128 * 2);
  float* T = (float*)p;      p += align_up((size_t)n * 128 * 4);
  unsigned char* Tb8 = (unsigned char*)p; p += align_up((size_t)n * 128);

  k_wsplit<<<8, 256, 0, stream>>>(W, Wh, Wl);
  k_ehist<<<nchunk, 256, 0, stream>>>(ep, ne, nbuck, ghist);
  k_bscan<<<nbuck, 256, 0, stream>>>(ghist, nchunk, nbuck, btot);
  k_bbase<<<1, 1024, 0, stream>>>(btot, nbuck, bbase);
  k_ebin<<<nchunk, 256, 0, stream>>>(ep, ne, nbuck, ghist, bbase, bins);
  k_bfinal<<<nbuck, 256, 0, stream>>>(bbase, btot, bins, n, deg, isd, offsets, csr_dst);
  k_gemm<<<(n + 63) / 64, 256, 0, stream>>>(X, Wh, Wl, b, isd, T, Tb8, n);
  k_gather<<<(n + 3) / 4, 256, 0, stream>>>(T, Tb8, deg, isd, offsets, csr_dst,
                                            mm, var, gamma, beta, out, n, ne);
}

// Round 11
// 92.489 us; speedup vs baseline: 1.1113x; 1.1113x over previous
//
#include <hip/hip_runtime.h>
#include <math.h>

#define BN_EPS 0.001f
#define CHUNK 2048          // edges per chunk; nchunk = ceil(ne/CHUNK) must be <= 512
#define MAXBUCK 1024        // nbuck = ceil(n/64) must be <= 1024

typedef __attribute__((ext_vector_type(8))) short bf16x8;
typedef __attribute__((ext_vector_type(4))) float f32x4;
typedef __attribute__((ext_vector_type(2))) float f32x2;

__device__ inline unsigned bf16rne(float f) {
  unsigned u = __float_as_uint(f);
  return (u + 0x7fffu + ((u >> 16) & 1u)) >> 16;
}

// ---------------- pass 1: per-chunk LDS histogram by bucket (src>>6) ----------------
__global__ __launch_bounds__(256) void k_ehist(const int2* __restrict__ ep, int ne,
                                               int nbuck, int* __restrict__ ghist) {
  __shared__ int h[MAXBUCK];
  int c = blockIdx.x, t = threadIdx.x;
  for (int i = t; i < nbuck; i += 256) h[i] = 0;
  __syncthreads();
  int base = c * CHUNK;
  int end = min(base + CHUNK, ne);
  for (int e = base + t; e < end; e += 256) atomicAdd(&h[ep[e].x >> 6], 1);
  __syncthreads();
  int* row = ghist + (size_t)c * nbuck;
  for (int i = t; i < nbuck; i += 256) row[i] = h[i];
}

// ---------------- pass 2a: per-bucket exclusive scan over chunks (in place) + totals ----
__global__ __launch_bounds__(512) void k_bscan(int* __restrict__ ghist, int nchunk,
                                               int nbuck, int* __restrict__ btot) {
  __shared__ int s0[512], s1[512];
  int b = blockIdx.x, t = threadIdx.x;
  int v = (t < nchunk) ? ghist[(size_t)t * nbuck + b] : 0;
  s0[t] = v;
  __syncthreads();
  int* src = s0; int* dst = s1;
  for (int off = 1; off < 512; off <<= 1) {
    int x = src[t];
    if (t >= off) x += src[t - off];
    dst[t] = x;
    __syncthreads();
    int* tmp = src; src = dst; dst = tmp;
  }
  if (t < nchunk) ghist[(size_t)t * nbuck + b] = src[t] - v;  // exclusive
  if (t == 0) btot[b] = src[511];                             // total
}

// ---------------- pass 2b: single-block exclusive scan of bucket totals ----------------
__global__ __launch_bounds__(1024) void k_bbase(const int* __restrict__ btot, int nbuck,
                                                int* __restrict__ bbase) {
  __shared__ int s0[1024], s1[1024];
  int t = threadIdx.x;
  int v = (t < nbuck) ? btot[t] : 0;
  s0[t] = v;
  __syncthreads();
  int* src = s0; int* dst = s1;
  for (int off = 1; off < 1024; off <<= 1) {
    int x = src[t];
    if (t >= off) x += src[t - off];
    dst[t] = x;
    __syncthreads();
    int* tmp = src; src = dst; dst = tmp;
  }
  if (t < nbuck) bbase[t] = src[t] - v;
}

// ---------------- pass 3: write packed records to exact slots (LDS cursors) ----------
// record: bits[16:0] = dst, bits[22:17] = src & 63
__global__ __launch_bounds__(256) void k_ebin(const int2* __restrict__ ep, int ne,
                                              int nbuck, const int* __restrict__ ghist,
                                              const int* __restrict__ bbase,
                                              unsigned* __restrict__ bins) {
  __shared__ int cur[MAXBUCK];
  int c = blockIdx.x, t = threadIdx.x;
  const int* row = ghist + (size_t)c * nbuck;
  for (int i = t; i < nbuck; i += 256) cur[i] = bbase[i] + row[i];
  __syncthreads();
  int base = c * CHUNK;
  int end = min(base + CHUNK, ne);
  for (int e = base + t; e < end; e += 256) {
    int2 p = ep[e];
    int pos = atomicAdd(&cur[p.x >> 6], 1);
    bins[pos] = (unsigned)p.y | ((unsigned)(p.x & 63) << 17);
  }
}

// ---------------- fused per-bucket: hist -> scan -> deg/isd/offsets -> CSR fill -------
__global__ __launch_bounds__(256) void k_bfinal(const int* __restrict__ bbase,
                                                const int* __restrict__ btot,
                                                const unsigned* __restrict__ bins,
                                                int n, int* __restrict__ deg,
                                                float* __restrict__ isd,
                                                int* __restrict__ offsets,
                                                int* __restrict__ csr_dst) {
  __shared__ int h[64];
  __shared__ int cur[64];
  int bk = blockIdx.x, t = threadIdx.x;
  if (t < 64) h[t] = 0;
  __syncthreads();
  int s = bbase[bk], cnt = btot[bk];
  for (int i = t; i < cnt; i += 256) atomicAdd(&h[bins[s + i] >> 17], 1);
  __syncthreads();
  if (t == 0) {
    int run = s;
    for (int j = 0; j < 64; ++j) { cur[j] = run; run += h[j]; }
  }
  __syncthreads();
  if (t < 64) {
    int node = (bk << 6) + t;
    if (node < n) {
      deg[node] = h[t];
      offsets[node] = cur[t];
      isd[node] = 1.0f / sqrtf((float)h[t]);  // deg==0 -> +inf, matches jnp.power
    }
  }
  __syncthreads();
  for (int i = t; i < cnt; i += 256) {
    unsigned r = bins[s + i];
    int pos = atomicAdd(&cur[r >> 17], 1);
    csr_dst[pos] = (int)(r & 0x1FFFFu);
  }
}

// ---------------- split-bf16 MFMA GEMM, B staged in LDS: T = X @ W + b ----------------
// One 1024-thread block per 256 rows (grid 196 <= 256 CUs -> 1 block/CU, one round).
// 16 waves x 16 rows x 128 cols. W split in-kernel to LDS fragment-major (64KB).
// Writes fp32 T and fp8 Tb8 = fp8(isd[row]*t[row]) (gather operand, 128B/row).
__global__ __launch_bounds__(1024, 4) void k_gemm(const float* __restrict__ X,
                                                  const float* __restrict__ W,
                                                  const float* __restrict__ b,
                                                  const float* __restrict__ isd,
                                                  float* __restrict__ T,
                                                  unsigned char* __restrict__ Tb8, int M) {
  __shared__ unsigned short WhL[16384];  // fragment-major: frag*512 + lane*8 + j
  __shared__ unsigned short WlL[16384];
  int tid = threadIdx.x;

  // ---- stage + split W (linear fragment-major writes, no transpose conflicts) ----
#pragma unroll
  for (int it = 0; it < 4; ++it) {
    int q = tid + it * 1024;   // float4 index, 4096 total
    int k = q >> 5;            // W row (k-dim)
    int c0 = (q & 31) * 4;     // starting col
    float4 v = ((const float4*)W)[q];
    float vv[4] = {v.x, v.y, v.z, v.w};
#pragma unroll
    for (int j2 = 0; j2 < 4; ++j2) {
      int col = c0 + j2;
      float x = vv[j2];
      unsigned short hh = (unsigned short)(__float_as_uint(x) >> 16);  // trunc hi
      float rem = x - __uint_as_float((unsigned)hh << 16);
      int frag = ((col >> 4) << 2) | (k >> 5);            // ct*4 + ks
      int ln = (((k >> 3) & 3) << 4) | (col & 15);        // lane
      int addr = frag * 512 + ln * 8 + (k & 7);
      WhL[addr] = hh;
      WlL[addr] = (unsigned short)bf16rne(rem);
    }
  }

  int wave = tid >> 6, lane = tid & 63;
  int r16 = lane & 15, kq = lane >> 4;
  int rowbase = blockIdx.x * 256 + wave * 16;
  int arow = rowbase + r16;
  bool aok = arow < M;
  const float* xr = X + ((size_t)arow << 7);

  // ---- load + split A fragments (16 rows x 128 k per wave) ----
  bf16x8 ah[4], al[4];
#pragma unroll
  for (int ks = 0; ks < 4; ++ks) {
    int k0 = ks * 32 + kq * 8;
    float4 v0 = aok ? *(const float4*)(xr + k0) : make_float4(0.f, 0.f, 0.f, 0.f);
    float4 v1 = aok ? *(const float4*)(xr + k0 + 4) : make_float4(0.f, 0.f, 0.f, 0.f);
    float f[8] = {v0.x, v0.y, v0.z, v0.w, v1.x, v1.y, v1.z, v1.w};
    bf16x8 h8, l8;
#pragma unroll
    for (int j = 0; j < 8; ++j) {
      unsigned short hh = (unsigned short)(__float_as_uint(f[j]) >> 16);
      float rem = f[j] - __uint_as_float((unsigned)hh << 16);
      h8[j] = (short)hh;
      l8[j] = (short)bf16rne(rem);
    }
    ah[ks] = h8;
    al[ks] = l8;
  }
  __syncthreads();

  // ---- MFMA: 8 col-tiles x 4 k-slices x 3 products, B from LDS ----
  f32x4 acc[8] = {};
#pragma unroll
  for (int ct = 0; ct < 8; ++ct) {
#pragma unroll
    for (int ks = 0; ks < 4; ++ks) {
      int base = (ct * 4 + ks) * 512 + lane * 8;
      bf16x8 bh = *(const bf16x8*)&WhL[base];
      bf16x8 bl = *(const bf16x8*)&WlL[base];
      acc[ct] = __builtin_amdgcn_mfma_f32_16x16x32_bf16(ah[ks], bh, acc[ct], 0, 0, 0);
      acc[ct] = __builtin_amdgcn_mfma_f32_16x16x32_bf16(ah[ks], bl, acc[ct], 0, 0, 0);
      acc[ct] = __builtin_amdgcn_mfma_f32_16x16x32_bf16(al[ks], bh, acc[ct], 0, 0, 0);
    }
  }

  // ---- epilogue: bias, fp32 T store, fp8 pack of isd-scaled value ----
  int orow[4];
  float isdr[4];
#pragma unroll
  for (int r = 0; r < 4; ++r) {
    orow[r] = rowbase + kq * 4 + r;
    isdr[r] = (orow[r] < M) ? isd[orow[r]] : 0.f;
  }
#pragma unroll
  for (int ct = 0; ct < 8; ++ct) {
    int col = ct * 16 + r16;
    float bias = b[col];
#pragma unroll
    for (int r = 0; r < 4; ++r) {
      float v = acc[ct][r] + bias;
      bool ok = orow[r] < M;
      if (ok) T[((size_t)orow[r] << 7) + col] = v;
      float sv = v * isdr[r];
      float other = __shfl_xor(sv, 1);  // col^1, same row
      int pk01 = __builtin_amdgcn_cvt_pk_fp8_f32(sv, other, 0, false);
      int pk23 = __shfl_xor(pk01, 2);
      if (ok && (r16 & 3) == 0) {
        unsigned dword = ((unsigned)pk01 & 0xFFFFu) | ((unsigned)pk23 << 16);
        *(unsigned*)&Tb8[((size_t)orow[r] << 7) + ct * 16 + r16] = dword;
      }
    }
  }
}

// ---------------- gather: one wave per node, fp8 rows (128B), 16 reads in flight ------
__global__ __launch_bounds__(256) void k_gather(
    const float* __restrict__ T, const unsigned char* __restrict__ Tb8,
    const int* __restrict__ deg, const float* __restrict__ isd,
    const int* __restrict__ offsets, const int* __restrict__ csr_dst,
    const float* __restrict__ mm, const float* __restrict__ var,
    const float* __restrict__ gamma, const float* __restrict__ beta,
    float* __restrict__ out, int n, int ne) {
  int wave = threadIdx.x >> 6;
  int lane = threadIdx.x & 63;
  int i = blockIdx.x * 4 + wave;
  if (i >= n) return;
  int degi = deg[i];
  int start = offsets[i];
  const unsigned short* rows = (const unsigned short*)Tb8;  // row stride 64 ushorts
  float sx[16] = {}, sy[16] = {};
  for (int e = 0; e < degi; e += 16) {
    int ii = start + e + (lane & 15);
    int dv = (ii < ne) ? csr_dst[ii] : 0;  // coalesced index load
    unsigned short r[16];
#pragma unroll
    for (int j = 0; j < 16; ++j) {
      int idx = __shfl(dv, j);
      r[j] = rows[((size_t)idx << 6) + lane];  // 2 fp8 cols per lane
    }
#pragma unroll
    for (int j = 0; j < 16; ++j) {
      int rr = (e + j < degi) ? (int)r[j] : 0;
      f32x2 f = __builtin_amdgcn_cvt_pk_f32_fp8(rr, false);
      sx[j] += f.x;
      sy[j] += f.y;
    }
  }
  float fx = (((sx[0] + sx[1]) + (sx[2] + sx[3])) + ((sx[4] + sx[5]) + (sx[6] + sx[7]))) +
             (((sx[8] + sx[9]) + (sx[10] + sx[11])) + ((sx[12] + sx[13]) + (sx[14] + sx[15])));
  float fy = (((sy[0] + sy[1]) + (sy[2] + sy[3])) + ((sy[4] + sy[5]) + (sy[6] + sy[7]))) +
             (((sy[8] + sy[9]) + (sy[10] + sy[11])) + ((sy[12] + sy[13]) + (sy[14] + sy[15])));
  float aggx = 0.f, aggy = 0.f;
  if (degi > 0) {
    float2 tv = ((const float2*)(T + ((size_t)i << 7)))[lane];
    float isi = isd[i];
    float di = (float)degi;
    aggx = 0.5f * (isi * fx) + 0.5f * (di * tv.x);
    aggy = 0.5f * (isi * fy) + 0.5f * (di * tv.y);
  }
  float2 mmv = ((const float2*)mm)[lane];
  float2 vv = ((const float2*)var)[lane];
  float2 gv = ((const float2*)gamma)[lane];
  float2 bv = ((const float2*)beta)[lane];
  float2 res;
  res.x = (aggx - mmv.x) * rsqrtf(vv.x + BN_EPS) * gv.x + bv.x;
  res.y = (aggy - mmv.y) * rsqrtf(vv.y + BN_EPS) * gv.y + bv.y;
  ((float2*)(out + ((size_t)i << 7)))[lane] = res;
}

static inline size_t align_up(size_t x) { return (x + 255) & ~(size_t)255; }

extern "C" void kernel_launch(void* const* d_in, const int* in_sizes, int n_in,
                              void* d_out, int out_size, void* d_ws, size_t ws_size,
                              hipStream_t stream) {
  const int2* ep = (const int2*)d_in[0];
  const float* X = (const float*)d_in[1];
  const float* W = (const float*)d_in[2];
  const float* b = (const float*)d_in[3];
  const float* gamma = (const float*)d_in[4];
  const float* beta = (const float*)d_in[5];
  const float* mm = (const float*)d_in[6];
  const float* var = (const float*)d_in[7];
  float* out = (float*)d_out;

  const int ne = in_sizes[0] / 2;
  const int n = in_sizes[1] / 128;
  const int nbuck = (n + 63) >> 6;              // <= MAXBUCK
  const int nchunk = (ne + CHUNK - 1) / CHUNK;  // <= 512

  char* p = (char*)d_ws;
  int* deg = (int*)p;        p += align_up((size_t)n * 4);
  float* isd = (float*)p;    p += align_up((size_t)n * 4);
  int* offsets = (int*)p;    p += align_up((size_t)n * 4);
  int* btot = (int*)p;       p += align_up((size_t)nbuck * 4);
  int* bbase = (int*)p;      p += align_up((size_t)nbuck * 4);
  int* ghist = (int*)p;      p += align_up((size_t)nchunk * nbuck * 4);
  int* csr_dst = (int*)p;    p += align_up((size_t)ne * 4);
  unsigned* bins = (unsigned*)p; p += align_up((size_t)ne * 4);
  float* T = (float*)p;      p += align_up((size_t)n * 128 * 4);
  unsigned char* Tb8 = (unsigned char*)p; p += align_up((size_t)n * 128);

  k_ehist<<<nchunk, 256, 0, stream>>>(ep, ne, nbuck, ghist);
  k_bscan<<<nbuck, 512, 0, stream>>>(ghist, nchunk, nbuck, btot);
  k_bbase<<<1, 1024, 0, stream>>>(btot, nbuck, bbase);
  k_ebin<<<nchunk, 256, 0, stream>>>(ep, ne, nbuck, ghist, bbase, bins);
  k_bfinal<<<nbuck, 256, 0, stream>>>(bbase, btot, bins, n, deg, isd, offsets, csr_dst);
  k_gemm<<<(n + 255) / 256, 1024, 0, stream>>>(X, W, b, isd, T, Tb8, n);
  k_gather<<<(n + 3) / 4, 256, 0, stream>>>(T, Tb8, deg, isd, offsets, csr_dst,
                                            mm, var, gamma, beta, out, n, ne);
}

// Round 12
// 81.815 us; speedup vs baseline: 1.2562x; 1.1305x over previous
//
#include <hip/hip_runtime.h>
#include <math.h>

#define BN_EPS 0.001f
#define CHUNK 2048          // edges per chunk; nchunk = ceil(ne/CHUNK) must be <= 512
#define MAXBUCK 1024        // nbuck = ceil(n/64) must be <= 1024

typedef __attribute__((ext_vector_type(8))) short bf16x8;
typedef __attribute__((ext_vector_type(4))) float f32x4;
typedef __attribute__((ext_vector_type(2))) float f32x2;

__device__ inline unsigned bf16rne(float f) {
  unsigned u = __float_as_uint(f);
  return (u + 0x7fffu + ((u >> 16) & 1u)) >> 16;
}

// ---------------- pass 1: per-chunk LDS histogram by bucket (src>>6) ----------------
__global__ __launch_bounds__(256) void k_ehist(const int2* __restrict__ ep, int ne,
                                               int nbuck, int* __restrict__ ghist) {
  __shared__ int h[MAXBUCK];
  int c = blockIdx.x, t = threadIdx.x;
  for (int i = t; i < nbuck; i += 256) h[i] = 0;
  __syncthreads();
  int base = c * CHUNK;
  int end = min(base + CHUNK, ne);
  for (int e = base + t; e < end; e += 256) atomicAdd(&h[ep[e].x >> 6], 1);
  __syncthreads();
  int* row = ghist + (size_t)c * nbuck;
  for (int i = t; i < nbuck; i += 256) row[i] = h[i];
}

// ---------------- pass 2a: per-bucket exclusive scan over chunks (in place) + totals ----
__global__ __launch_bounds__(512) void k_bscan(int* __restrict__ ghist, int nchunk,
                                               int nbuck, int* __restrict__ btot) {
  __shared__ int s0[512], s1[512];
  int b = blockIdx.x, t = threadIdx.x;
  int v = (t < nchunk) ? ghist[(size_t)t * nbuck + b] : 0;
  s0[t] = v;
  __syncthreads();
  int* src = s0; int* dst = s1;
  for (int off = 1; off < 512; off <<= 1) {
    int x = src[t];
    if (t >= off) x += src[t - off];
    dst[t] = x;
    __syncthreads();
    int* tmp = src; src = dst; dst = tmp;
  }
  if (t < nchunk) ghist[(size_t)t * nbuck + b] = src[t] - v;  // exclusive
  if (t == 0) btot[b] = src[511];                             // total
}

// ---------------- pass 2b: single-block exclusive scan of bucket totals ----------------
__global__ __launch_bounds__(1024) void k_bbase(const int* __restrict__ btot, int nbuck,
                                                int* __restrict__ bbase) {
  __shared__ int s0[1024], s1[1024];
  int t = threadIdx.x;
  int v = (t < nbuck) ? btot[t] : 0;
  s0[t] = v;
  __syncthreads();
  int* src = s0; int* dst = s1;
  for (int off = 1; off < 1024; off <<= 1) {
    int x = src[t];
    if (t >= off) x += src[t - off];
    dst[t] = x;
    __syncthreads();
    int* tmp = src; src = dst; dst = tmp;
  }
  if (t < nbuck) bbase[t] = src[t] - v;
}

// ---------------- pass 3: write packed records to exact slots (LDS cursors) ----------
// record: bits[16:0] = dst, bits[22:17] = src & 63
__global__ __launch_bounds__(256) void k_ebin(const int2* __restrict__ ep, int ne,
                                              int nbuck, const int* __restrict__ ghist,
                                              const int* __restrict__ bbase,
                                              unsigned* __restrict__ bins) {
  __shared__ int cur[MAXBUCK];
  int c = blockIdx.x, t = threadIdx.x;
  const int* row = ghist + (size_t)c * nbuck;
  for (int i = t; i < nbuck; i += 256) cur[i] = bbase[i] + row[i];
  __syncthreads();
  int base = c * CHUNK;
  int end = min(base + CHUNK, ne);
  for (int e = base + t; e < end; e += 256) {
    int2 p = ep[e];
    int pos = atomicAdd(&cur[p.x >> 6], 1);
    bins[pos] = (unsigned)p.y | ((unsigned)(p.x & 63) << 17);
  }
}

// ---------------- fused per-bucket: hist -> scan -> deg/isd/offsets -> CSR fill -------
__global__ __launch_bounds__(256) void k_bfinal(const int* __restrict__ bbase,
                                                const int* __restrict__ btot,
                                                const unsigned* __restrict__ bins,
                                                int n, int* __restrict__ deg,
                                                float* __restrict__ isd,
                                                int* __restrict__ offsets,
                                                int* __restrict__ csr_dst) {
  __shared__ int h[64];
  __shared__ int cur[64];
  int bk = blockIdx.x, t = threadIdx.x;
  if (t < 64) h[t] = 0;
  __syncthreads();
  int s = bbase[bk], cnt = btot[bk];
  for (int i = t; i < cnt; i += 256) atomicAdd(&h[bins[s + i] >> 17], 1);
  __syncthreads();
  if (t == 0) {
    int run = s;
    for (int j = 0; j < 64; ++j) { cur[j] = run; run += h[j]; }
  }
  __syncthreads();
  if (t < 64) {
    int node = (bk << 6) + t;
    if (node < n) {
      deg[node] = h[t];
      offsets[node] = cur[t];
      isd[node] = 1.0f / sqrtf((float)h[t]);  // deg==0 -> +inf, matches jnp.power
    }
  }
  __syncthreads();
  for (int i = t; i < cnt; i += 256) {
    unsigned r = bins[s + i];
    int pos = atomicAdd(&cur[r >> 17], 1);
    csr_dst[pos] = (int)(r & 0x1FFFFu);
  }
}

// ---------------- split-bf16 MFMA GEMM, B staged in LDS: T = X @ W + b ----------------
// One 1024-thread block per 256 rows (grid 196 <= 256 CUs -> 1 block/CU, one round).
// 16 waves x 16 rows x 128 cols. W split in-kernel to LDS fragment-major (64KB).
// Writes fp32 T and fp8 Tb8 = fp8(isd[row]*t[row]) (gather operand, 128B/row).
__global__ __launch_bounds__(1024, 4) void k_gemm(const float* __restrict__ X,
                                                  const float* __restrict__ W,
                                                  const float* __restrict__ b,
                                                  const float* __restrict__ isd,
                                                  float* __restrict__ T,
                                                  unsigned char* __restrict__ Tb8, int M) {
  __shared__ unsigned short WhL[16384];  // fragment-major: frag*512 + lane*8 + j
  __shared__ unsigned short WlL[16384];
  int tid = threadIdx.x;

  // ---- stage + split W (linear fragment-major writes) ----
#pragma unroll
  for (int it = 0; it < 4; ++it) {
    int q = tid + it * 1024;   // float4 index, 4096 total
    int k = q >> 5;            // W row (k-dim)
    int c0 = (q & 31) * 4;     // starting col
    float4 v = ((const float4*)W)[q];
    float vv[4] = {v.x, v.y, v.z, v.w};
#pragma unroll
    for (int j2 = 0; j2 < 4; ++j2) {
      int col = c0 + j2;
      float x = vv[j2];
      unsigned short hh = (unsigned short)(__float_as_uint(x) >> 16);  // trunc hi
      float rem = x - __uint_as_float((unsigned)hh << 16);
      int frag = ((col >> 4) << 2) | (k >> 5);            // ct*4 + ks
      int ln = (((k >> 3) & 3) << 4) | (col & 15);        // lane
      int addr = frag * 512 + ln * 8 + (k & 7);
      WhL[addr] = hh;
      WlL[addr] = (unsigned short)bf16rne(rem);
    }
  }

  int wave = tid >> 6, lane = tid & 63;
  int r16 = lane & 15, kq = lane >> 4;
  int rowbase = blockIdx.x * 256 + wave * 16;
  int arow = rowbase + r16;
  bool aok = arow < M;
  const float* xr = X + ((size_t)arow << 7);

  // ---- load + split A fragments (16 rows x 128 k per wave) ----
  bf16x8 ah[4], al[4];
#pragma unroll
  for (int ks = 0; ks < 4; ++ks) {
    int k0 = ks * 32 + kq * 8;
    float4 v0 = aok ? *(const float4*)(xr + k0) : make_float4(0.f, 0.f, 0.f, 0.f);
    float4 v1 = aok ? *(const float4*)(xr + k0 + 4) : make_float4(0.f, 0.f, 0.f, 0.f);
    float f[8] = {v0.x, v0.y, v0.z, v0.w, v1.x, v1.y, v1.z, v1.w};
    bf16x8 h8, l8;
#pragma unroll
    for (int j = 0; j < 8; ++j) {
      unsigned short hh = (unsigned short)(__float_as_uint(f[j]) >> 16);
      float rem = f[j] - __uint_as_float((unsigned)hh << 16);
      h8[j] = (short)hh;
      l8[j] = (short)bf16rne(rem);
    }
    ah[ks] = h8;
    al[ks] = l8;
  }
  __syncthreads();

  // ---- MFMA: 8 col-tiles x 4 k-slices x 3 products, B from LDS ----
  f32x4 acc[8] = {};
#pragma unroll
  for (int ct = 0; ct < 8; ++ct) {
#pragma unroll
    for (int ks = 0; ks < 4; ++ks) {
      int base = (ct * 4 + ks) * 512 + lane * 8;
      bf16x8 bh = *(const bf16x8*)&WhL[base];
      bf16x8 bl = *(const bf16x8*)&WlL[base];
      acc[ct] = __builtin_amdgcn_mfma_f32_16x16x32_bf16(ah[ks], bh, acc[ct], 0, 0, 0);
      acc[ct] = __builtin_amdgcn_mfma_f32_16x16x32_bf16(ah[ks], bl, acc[ct], 0, 0, 0);
      acc[ct] = __builtin_amdgcn_mfma_f32_16x16x32_bf16(al[ks], bh, acc[ct], 0, 0, 0);
    }
  }

  // ---- epilogue: bias, fp32 T store, fp8 pack of isd-scaled value ----
  int orow[4];
  float isdr[4];
#pragma unroll
  for (int r = 0; r < 4; ++r) {
    orow[r] = rowbase + kq * 4 + r;
    isdr[r] = (orow[r] < M) ? isd[orow[r]] : 0.f;
  }
#pragma unroll
  for (int ct = 0; ct < 8; ++ct) {
    int col = ct * 16 + r16;
    float bias = b[col];
#pragma unroll
    for (int r = 0; r < 4; ++r) {
      float v = acc[ct][r] + bias;
      bool ok = orow[r] < M;
      if (ok) T[((size_t)orow[r] << 7) + col] = v;
      float sv = v * isdr[r];
      float other = __shfl_xor(sv, 1);  // col^1, same row
      int pk01 = __builtin_amdgcn_cvt_pk_fp8_f32(sv, other, 0, false);
      int pk23 = __shfl_xor(pk01, 2);
      if (ok && (r16 & 3) == 0) {
        unsigned dword = ((unsigned)pk01 & 0xFFFFu) | ((unsigned)pk23 << 16);
        *(unsigned*)&Tb8[((size_t)orow[r] << 7) + ct * 16 + r16] = dword;
      }
    }
  }
}

// ---------------- gather: HALF-WAVE per node (2 nodes/wave), fp8 dword loads ----------
// Lanes 0-31 own node 2p, lanes 32-63 own node 2p+1. Lane covers 4 fp8 cols (dword).
// Every vmem/VALU instruction serves two edges (one per half).
__global__ __launch_bounds__(256) void k_gather(
    const float* __restrict__ T, const unsigned char* __restrict__ Tb8,
    const int* __restrict__ deg, const float* __restrict__ isd,
    const int* __restrict__ offsets, const int* __restrict__ csr_dst,
    const float* __restrict__ mm, const float* __restrict__ var,
    const float* __restrict__ gamma, const float* __restrict__ beta,
    float* __restrict__ out, int n) {
  int wave = threadIdx.x >> 6;
  int lane = threadIdx.x & 63;
  int half = lane >> 5;
  int l32 = lane & 31;
  int pair = blockIdx.x * 4 + wave;
  int i = 2 * pair + half;
  if (2 * pair >= n) return;
  bool iok = i < n;
  int degi = iok ? deg[i] : 0;
  int start = iok ? offsets[i] : 0;
  int dother = __shfl(degi, lane ^ 32);
  int dmax = max(degi, dother);
  const unsigned* rows = (const unsigned*)Tb8;  // 32 dwords per row (128B)

  f32x4 acc[8] = {};
  for (int e = 0; e < dmax; e += 8) {
    int sl = l32 & 7;
    int dv = (e + sl < degi) ? csr_dst[start + e + sl] : i;  // self row when masked
    unsigned r8[8];
#pragma unroll
    for (int j = 0; j < 8; ++j) {
      int idx = __shfl(dv, (half << 5) + j);  // j-th index of MY node
      r8[j] = rows[((size_t)idx << 5) + l32];
    }
#pragma unroll
    for (int j = 0; j < 8; ++j) {
      int rr = (e + j < degi) ? (int)r8[j] : 0;
      f32x2 f01 = __builtin_amdgcn_cvt_pk_f32_fp8(rr, false);
      f32x2 f23 = __builtin_amdgcn_cvt_pk_f32_fp8(rr, true);
      acc[j][0] += f01.x;
      acc[j][1] += f01.y;
      acc[j][2] += f23.x;
      acc[j][3] += f23.y;
    }
  }
  f32x4 s = ((acc[0] + acc[1]) + (acc[2] + acc[3])) + ((acc[4] + acc[5]) + (acc[6] + acc[7]));

  if (!iok) return;
  float4 aggv = make_float4(0.f, 0.f, 0.f, 0.f);
  if (degi > 0) {
    float4 tv = ((const float4*)(T + ((size_t)i << 7)))[l32];
    float isi = isd[i];
    float di = (float)degi;
    aggv.x = 0.5f * (isi * s[0]) + 0.5f * (di * tv.x);
    aggv.y = 0.5f * (isi * s[1]) + 0.5f * (di * tv.y);
    aggv.z = 0.5f * (isi * s[2]) + 0.5f * (di * tv.z);
    aggv.w = 0.5f * (isi * s[3]) + 0.5f * (di * tv.w);
  }
  float4 mmv = ((const float4*)mm)[l32];
  float4 vv = ((const float4*)var)[l32];
  float4 gv = ((const float4*)gamma)[l32];
  float4 bv = ((const float4*)beta)[l32];
  float4 res;
  res.x = (aggv.x - mmv.x) * rsqrtf(vv.x + BN_EPS) * gv.x + bv.x;
  res.y = (aggv.y - mmv.y) * rsqrtf(vv.y + BN_EPS) * gv.y + bv.y;
  res.z = (aggv.z - mmv.z) * rsqrtf(vv.z + BN_EPS) * gv.z + bv.z;
  res.w = (aggv.w - mmv.w) * rsqrtf(vv.w + BN_EPS) * gv.w + bv.w;
  ((float4*)(out + ((size_t)i << 7)))[l32] = res;
}

static inline size_t align_up(size_t x) { return (x + 255) & ~(size_t)255; }

extern "C" void kernel_launch(void* const* d_in, const int* in_sizes, int n_in,
                              void* d_out, int out_size, void* d_ws, size_t ws_size,
                              hipStream_t stream) {
  const int2* ep = (const int2*)d_in[0];
  const float* X = (const float*)d_in[1];
  const float* W = (const float*)d_in[2];
  const float* b = (const float*)d_in[3];
  const float* gamma = (const float*)d_in[4];
  const float* beta = (const float*)d_in[5];
  const float* mm = (const float*)d_in[6];
  const float* var = (const float*)d_in[7];
  float* out = (float*)d_out;

  const int ne = in_sizes[0] / 2;
  const int n = in_sizes[1] / 128;
  const int nbuck = (n + 63) >> 6;              // <= MAXBUCK
  const int nchunk = (ne + CHUNK - 1) / CHUNK;  // <= 512

  char* p = (char*)d_ws;
  int* deg = (int*)p;        p += align_up((size_t)n * 4);
  float* isd = (float*)p;    p += align_up((size_t)n * 4);
  int* offsets = (int*)p;    p += align_up((size_t)n * 4);
  int* btot = (int*)p;       p += align_up((size_t)nbuck * 4);
  int* bbase = (int*)p;      p += align_up((size_t)nbuck * 4);
  int* ghist = (int*)p;      p += align_up((size_t)nchunk * nbuck * 4);
  int* csr_dst = (int*)p;    p += align_up((size_t)ne * 4);
  unsigned* bins = (unsigned*)p; p += align_up((size_t)ne * 4);
  float* T = (float*)p;      p += align_up((size_t)n * 128 * 4);
  unsigned char* Tb8 = (unsigned char*)p; p += align_up((size_t)n * 128);

  k_ehist<<<nchunk, 256, 0, stream>>>(ep, ne, nbuck, ghist);
  k_bscan<<<nbuck, 512, 0, stream>>>(ghist, nchunk, nbuck, btot);
  k_bbase<<<1, 1024, 0, stream>>>(btot, nbuck, bbase);
  k_ebin<<<nchunk, 256, 0, stream>>>(ep, ne, nbuck, ghist, bbase, bins);
  k_bfinal<<<nbuck, 256, 0, stream>>>(bbase, btot, bins, n, deg, isd, offsets, csr_dst);
  k_gemm<<<(n + 255) / 256, 1024, 0, stream>>>(X, W, b, isd, T, Tb8, n);
  int pairs = (n + 1) / 2;
  k_gather<<<(pairs + 3) / 4, 256, 0, stream>>>(T, Tb8, deg, isd, offsets, csr_dst,
                                                mm, var, gamma, beta, out, n);
}